// Round 4
// baseline (83.453 us; speedup 1.0000x reference)
//
#include <hip/hip_runtime.h>

// PolynomialLayer: in (N,3) f32 -> out (N,10) f32
// out row = [1, x0, x1, x2, x0^2, x0*x1, x0*x2, x1^2, x1*x2, x2^2]
//
// R4: stride-5 identity LDS staging.
//   - 2 rows/thread = 20 out floats = 5 float4 per lane.
//   - LDS is float4-granular, wave-private, laid out OUTPUT-LINEAR:
//     lane writes lds4[5*lane+j] (stride 5 is odd -> coprime with the 8
//     four-bank groups -> write side hits all 8 groups per 8 lanes = LDS
//     b128 bandwidth floor, zero conflicts). Read-back lds4[q*64+lane] is
//     bank-floor too, and needs no index arithmetic at all.
//   - Stores: 5x global_store_dwordx4, each 64 consecutive float4 = 1KB
//     full lines (the fill-kernel pattern that runs ~6.9 TB/s here).
//   - 20 KB LDS/block -> 8 blocks/CU -> 32 waves/CU = 100% occupancy.
//   - Wave-private slices -> no __syncthreads.

#define BLOCK 256

__global__ __launch_bounds__(BLOCK) void poly_s5_kernel(const float2* __restrict__ in2,
                                                        float4* __restrict__ out4,
                                                        int nPairs) {
    __shared__ float4 lds4[4][320];  // 4 waves x 5 KB = 20 KB
    const int lane = threadIdx.x & 63;
    const int wid = threadIdx.x >> 6;
    float4* wlds = lds4[wid];

    int idx = blockIdx.x * BLOCK + threadIdx.x;
    int stride = gridDim.x * BLOCK;
    for (int c = idx;; c += stride) {
        int waveBase = c - lane;  // wave-uniform pair index of lane 0
        if (waveBase >= nPairs) break;
        bool fullWave = (waveBase + 64 <= nPairs);
        bool valid = (c < nPairs);

        float4 v0, v1, v2, v3, v4;
        if (valid) {
            size_t pb = 3 * (size_t)c;
            float2 a = in2[pb + 0];
            float2 b = in2[pb + 1];
            float2 d = in2[pb + 2];
            float xa0 = a.x, xa1 = a.y, xa2 = b.x;   // row A = 2c
            float xb0 = b.y, xb1 = d.x, xb2 = d.y;   // row B = 2c+1
            v0 = make_float4(1.0f, xa0, xa1, xa2);
            v1 = make_float4(xa0 * xa0, xa0 * xa1, xa0 * xa2, xa1 * xa1);
            v2 = make_float4(xa1 * xa2, xa2 * xa2, 1.0f, xb0);
            v3 = make_float4(xb1, xb2, xb0 * xb0, xb0 * xb1);
            v4 = make_float4(xb0 * xb2, xb1 * xb1, xb1 * xb2, xb2 * xb2);
        } else {
            v0 = v1 = v2 = v3 = v4 = make_float4(0.f, 0.f, 0.f, 0.f);
        }

        if (fullWave) {
            // stage: output-linear layout, stride-5 writes (bank-floor)
            float4* myrow = &wlds[5 * lane];
            myrow[0] = v0; myrow[1] = v1; myrow[2] = v2; myrow[3] = v3; myrow[4] = v4;
            // drain: lane-consecutive reads + 1KB-contiguous stores
            float4* wout = out4 + 5ll * (long long)waveBase;
#pragma unroll
            for (int q = 0; q < 5; ++q) {
                int j = q * 64 + lane;
                wout[j] = wlds[j];
            }
        } else if (valid) {
            // rare ragged wave: direct per-thread stores
            float4* po = out4 + 5ll * (long long)c;
            po[0] = v0; po[1] = v1; po[2] = v2; po[3] = v3; po[4] = v4;
        }
    }
}

// Scalar tail for an odd final row (not hit at N=8e6).
__global__ void poly_tail_kernel(const float* __restrict__ in,
                                 float* __restrict__ out,
                                 int startRow, int nRows) {
    int i = startRow + blockIdx.x * blockDim.x + threadIdx.x;
    if (i >= nRows) return;
    float x0 = in[3 * (long long)i + 0];
    float x1 = in[3 * (long long)i + 1];
    float x2 = in[3 * (long long)i + 2];
    float* p = &out[10 * (long long)i];
    p[0] = 1.0f; p[1] = x0; p[2] = x1; p[3] = x2;
    p[4] = x0 * x0; p[5] = x0 * x1; p[6] = x0 * x2;
    p[7] = x1 * x1; p[8] = x1 * x2; p[9] = x2 * x2;
}

extern "C" void kernel_launch(void* const* d_in, const int* in_sizes, int n_in,
                              void* d_out, int out_size, void* d_ws, size_t ws_size,
                              hipStream_t stream) {
    const float* in = (const float*)d_in[0];
    float* out = (float*)d_out;
    int nRows = in_sizes[0] / 3;
    int nPairs = nRows / 2;

    if (nPairs > 0) {
        int blocks = (nPairs + BLOCK - 1) / BLOCK;
        if (blocks > 2048) blocks = 2048;  // 8 blocks/CU x 256 CU, grid-stride
        poly_s5_kernel<<<blocks, BLOCK, 0, stream>>>((const float2*)in, (float4*)out, nPairs);
    }
    int done = nPairs * 2;
    if (done < nRows) {  // odd final row
        poly_tail_kernel<<<1, 64, 0, stream>>>(in, out, done, nRows);
    }
}

// Round 6
// 64.709 us; speedup vs baseline: 1.2897x; 1.2897x over previous
//
#include <hip/hip_runtime.h>

// PolynomialLayer: in (N,3) f32 -> out (N,10) f32
// out row = [1, x0, x1, x2, x0^2, x0*x1, x0*x2, x1^2, x1*x2, x2^2]
//
// R6 = R4 (stride-5 identity LDS staging, fully coalesced 1KB stores)
//      + NONTEMPORAL output stores (fixed: __builtin_nontemporal_store
//      needs a clang native vector type, not HIP's float4 struct).
// Rationale: output is write-once-never-read; nt stores skip L2/L3
// allocation so the 320 MB/replay write stream stops evicting the 96 MB
// input from the 256 MB Infinity Cache. Input can then stay L3-resident
// across graph replays -> HBM traffic approaches write-only 320 MB.

#define BLOCK 256

typedef float fx4 __attribute__((ext_vector_type(4)));

__device__ __forceinline__ void nt_store4(float4* dst, const float4& v) {
    __builtin_nontemporal_store(*reinterpret_cast<const fx4*>(&v),
                                reinterpret_cast<fx4*>(dst));
}

__global__ __launch_bounds__(BLOCK) void poly_s5nt_kernel(const float2* __restrict__ in2,
                                                          float4* __restrict__ out4,
                                                          int nPairs) {
    __shared__ float4 lds4[4][320];  // 4 waves x 5 KB = 20 KB
    const int lane = threadIdx.x & 63;
    const int wid = threadIdx.x >> 6;
    float4* wlds = lds4[wid];

    int idx = blockIdx.x * BLOCK + threadIdx.x;
    int stride = gridDim.x * BLOCK;
    for (int c = idx;; c += stride) {
        int waveBase = c - lane;  // wave-uniform pair index of lane 0
        if (waveBase >= nPairs) break;
        bool fullWave = (waveBase + 64 <= nPairs);
        bool valid = (c < nPairs);

        float4 v0, v1, v2, v3, v4;
        if (valid) {
            size_t pb = 3 * (size_t)c;
            float2 a = in2[pb + 0];
            float2 b = in2[pb + 1];
            float2 d = in2[pb + 2];
            float xa0 = a.x, xa1 = a.y, xa2 = b.x;   // row A = 2c
            float xb0 = b.y, xb1 = d.x, xb2 = d.y;   // row B = 2c+1
            v0 = make_float4(1.0f, xa0, xa1, xa2);
            v1 = make_float4(xa0 * xa0, xa0 * xa1, xa0 * xa2, xa1 * xa1);
            v2 = make_float4(xa1 * xa2, xa2 * xa2, 1.0f, xb0);
            v3 = make_float4(xb1, xb2, xb0 * xb0, xb0 * xb1);
            v4 = make_float4(xb0 * xb2, xb1 * xb1, xb1 * xb2, xb2 * xb2);
        } else {
            v0 = v1 = v2 = v3 = v4 = make_float4(0.f, 0.f, 0.f, 0.f);
        }

        if (fullWave) {
            // stage: output-linear layout, stride-5 writes (bank-floor)
            float4* myrow = &wlds[5 * lane];
            myrow[0] = v0; myrow[1] = v1; myrow[2] = v2; myrow[3] = v3; myrow[4] = v4;
            // drain: lane-consecutive reads + 1KB-contiguous nt stores
            float4* wout = out4 + 5ll * (long long)waveBase;
#pragma unroll
            for (int q = 0; q < 5; ++q) {
                int j = q * 64 + lane;
                float4 t = wlds[j];
                nt_store4(&wout[j], t);
            }
        } else if (valid) {
            // rare ragged wave: direct per-thread stores
            float4* po = out4 + 5ll * (long long)c;
            nt_store4(&po[0], v0);
            nt_store4(&po[1], v1);
            nt_store4(&po[2], v2);
            nt_store4(&po[3], v3);
            nt_store4(&po[4], v4);
        }
    }
}

// Scalar tail for an odd final row (not hit at N=8e6).
__global__ void poly_tail_kernel(const float* __restrict__ in,
                                 float* __restrict__ out,
                                 int startRow, int nRows) {
    int i = startRow + blockIdx.x * blockDim.x + threadIdx.x;
    if (i >= nRows) return;
    float x0 = in[3 * (long long)i + 0];
    float x1 = in[3 * (long long)i + 1];
    float x2 = in[3 * (long long)i + 2];
    float* p = &out[10 * (long long)i];
    p[0] = 1.0f; p[1] = x0; p[2] = x1; p[3] = x2;
    p[4] = x0 * x0; p[5] = x0 * x1; p[6] = x0 * x2;
    p[7] = x1 * x1; p[8] = x1 * x2; p[9] = x2 * x2;
}

extern "C" void kernel_launch(void* const* d_in, const int* in_sizes, int n_in,
                              void* d_out, int out_size, void* d_ws, size_t ws_size,
                              hipStream_t stream) {
    const float* in = (const float*)d_in[0];
    float* out = (float*)d_out;
    int nRows = in_sizes[0] / 3;
    int nPairs = nRows / 2;

    if (nPairs > 0) {
        int blocks = (nPairs + BLOCK - 1) / BLOCK;
        if (blocks > 2048) blocks = 2048;  // 8 blocks/CU x 256 CU, grid-stride
        poly_s5nt_kernel<<<blocks, BLOCK, 0, stream>>>((const float2*)in, (float4*)out, nPairs);
    }
    int done = nPairs * 2;
    if (done < nRows) {  // odd final row
        poly_tail_kernel<<<1, 64, 0, stream>>>(in, out, done, nRows);
    }
}